// Round 4
// baseline (451.128 us; speedup 1.0000x reference)
//
#include <hip/hip_runtime.h>
#include <hip/hip_bf16.h>
#include <math.h>

#define N_PTS 20000
#define C_IN 128
#define C_OUT 64
#define M_PTS (N_PTS*8)
#define EPS 1e-5f

typedef __attribute__((ext_vector_type(8))) short short8;
typedef __attribute__((ext_vector_type(4))) float float4v;

__device__ __forceinline__ ushort f2bf(float f){
    unsigned int i = __float_as_uint(f);
    unsigned int r = i + 0x7fffu + ((i >> 16) & 1u);
    return (ushort)(r >> 16);
}
__device__ __forceinline__ float bf2f(ushort u){ return __uint_as_float(((unsigned int)u) << 16); }
__device__ __forceinline__ float silu(float z){ return z / (1.f + expf(-z)); }

// stats layout (fp32, ws): [0..31] gn1 group sum, [32..63] gn1 group sumsq,
//                          [64..127] gn2 ch sum, [128..191] gn2 ch sumsq

// ================= K1: wprep1 + wprep2 + pg_init(+zero rows) + gn1_partial =================
// blocks: [0,864) wprep1, [864,1296) wprep2, [1296,1424) pg_init, [1424,1936) gn1
__global__ void __launch_bounds__(256) prep_kernel(
    const float* __restrict__ W1, const float* __restrict__ W2,
    ushort* __restrict__ Wt1, ushort* __restrict__ Wt2,
    int* __restrict__ pg, ushort* __restrict__ h, ushort* __restrict__ h2,
    const float* __restrict__ x, float* __restrict__ stats)
{
    const int b = blockIdx.x, tid = threadIdx.x;
    if (b < 864){
        // Wt1 fragment order: idx = (((t*4+kb)*4+nb)*64+l)*8+j, KB=4
        int idx = b * 256 + tid;
        int j = idx & 7, l = (idx >> 3) & 63, nb = (idx >> 9) & 3, kb = (idx >> 11) & 3, t = idx >> 13;
        int ci = kb * 32 + (l >> 4) * 8 + j, co = nb * 16 + (l & 15);
        Wt1[idx] = f2bf(W1[(t * C_IN + ci) * 64 + co]);
    } else if (b < 1296){
        // Wt2 fragment order: idx = (((t*2+kb)*4+nb)*64+l)*8+j, KB=2
        int idx = (b - 864) * 256 + tid;
        int j = idx & 7, l = (idx >> 3) & 63, nb = (idx >> 9) & 3, kb = (idx >> 11) & 1, t = idx >> 12;
        int ci = kb * 32 + (l >> 4) * 8 + j, co = nb * 16 + (l & 15);
        Wt2[idx] = f2bf(W2[(t * C_OUT + ci) * 64 + co]);
    } else if (b < 1424){
        int i = (b - 1296) * 256 + tid;
        pg[i] = -1;
        if (b == 1296){
            if (tid < C_IN) h[(size_t)N_PTS * C_IN + tid] = 0;    // zero feature row (conv1)
            if (tid < C_OUT) h2[(size_t)M_PTS * C_OUT + tid] = 0; // zero feature row (conv2)
        }
    } else {
        // gn1 partial: 512 blocks, grid-stride rows, LDS + global atomics
        __shared__ float ls[64];
        if (tid < 64) ls[tid] = 0.f;
        __syncthreads();
        const int g = tid & 31;
        const int r0 = (b - 1424) * 8 + (tid >> 5);
        float sum = 0.f, sq = 0.f;
        for (int r = r0; r < N_PTS; r += 4096){
            float4 v = *(const float4*)(x + (size_t)r * C_IN + g * 4);
            sum += v.x + v.y + v.z + v.w;
            sq  += v.x*v.x + v.y*v.y + v.z*v.z + v.w*v.w;
        }
        atomicAdd(&ls[g], sum);
        atomicAdd(&ls[32 + g], sq);
        __syncthreads();
        if (tid < 64) atomicAdd(&stats[tid], ls[tid]);
    }
}

// ================= K2: pg_scatter + h_compute + skip =================
// blocks: [0,79) scatter, [79,2579) h (vec4), [2579,7579) skip
__global__ void __launch_bounds__(256) mid_kernel(
    const int* __restrict__ cds, int* __restrict__ pg,
    const float* __restrict__ x, const float* __restrict__ stats,
    const float* __restrict__ g1, const float* __restrict__ b1, ushort* __restrict__ h,
    const float* __restrict__ Wsk, const float* __restrict__ bsk, float* __restrict__ s)
{
    __shared__ float w[C_IN * C_OUT];
    const int b = blockIdx.x, tid = threadIdx.x;
    if (b < 79){
        int i = b * 256 + tid;
        if (i < N_PTS){
            const int* cd = cds + i * 4;
            pg[(cd[1] * 32 + cd[2]) * 32 + cd[3]] = i;
        }
    } else if (b < 2579){
        int i = ((b - 79) * 256 + tid) * 4;
        int c0 = i & (C_IN - 1);                  // multiple of 4 -> one group
        int g = c0 >> 2;
        float mu = stats[g] * (1.0f / (N_PTS * 4.0f));
        float var = stats[32 + g] * (1.0f / (N_PTS * 4.0f)) - mu * mu;
        float rs = rsqrtf(var + EPS);
        float4 v = *(const float4*)(x + i);
        ushort4 o;
        o.x = f2bf(silu((v.x - mu) * rs * g1[c0+0] + b1[c0+0]));
        o.y = f2bf(silu((v.y - mu) * rs * g1[c0+1] + b1[c0+1]));
        o.z = f2bf(silu((v.z - mu) * rs * g1[c0+2] + b1[c0+2]));
        o.w = f2bf(silu((v.w - mu) * rs * g1[c0+3] + b1[c0+3]));
        *(ushort4*)(h + i) = o;
    } else {
        for (int j = tid; j < C_IN * C_OUT; j += 256) w[j] = Wsk[j];
        __syncthreads();
        int co = tid & 63, pr = tid >> 6;
        int p = (b - 2579) * 4 + pr;
        const float* xr = x + (size_t)p * C_IN;
        float a = bsk[co];
        for (int cb = 0; cb < C_IN; cb += 4){
            float4 v = *(const float4*)(xr + cb);
            a += v.x * w[(cb+0)*64+co] + v.y * w[(cb+1)*64+co]
               + v.z * w[(cb+2)*64+co] + v.w * w[(cb+3)*64+co];
        }
        s[(size_t)p * C_OUT + co] = a;
    }
}

// ================= conv: tap-split 2-wave implicit GEMM, M=64 =================
// block = 128 threads (2 waves), M-tile 64 children, N = 64.
// Wave 0 accumulates taps [0,14), wave 1 taps [14,27); wave 1 dumps its partial
// acc to LDS (conflict-free [c][lane] float4 layout), one barrier, wave 0 merges
// and runs the epilogue. A/B traffic unchanged vs 1-wave M=64 (each tap read once
// per block), serial tap chain halves, wave supply doubles (5000 waves ~19.5/CU).
// Rows are pre-gathered per wave (static rows[] under full unroll), exchanged by
// __shfl (no barrier inside the MFMA loop).
// CHILD=0 (conv1): feat row = parent; writes hf1 bf16; fused GN2 sums.
// CHILD=1 (conv2): feat row = child; adds skip; writes fp32 out.
template<int CIN, int CHILD, int TBEG, int TEND>
__device__ __forceinline__ void conv_taps(
    const ushort* __restrict__ feat, const int* __restrict__ pg,
    const ushort* __restrict__ Wt,
    int cx0, int cy0, int cz0, int l, int r16, int qd,
    float4v acc[16])
{
    constexpr int KB = CIN / 32;
    constexpr int ZROW = CHILD ? (8 * N_PTS) : N_PTS;   // zero feature row index
    int rows[TEND - TBEG];
#pragma unroll
    for (int t = TBEG; t < TEND; t++){
        const int dx = t / 9 - 1, dy = (t / 3) % 3 - 1, dz = t % 3 - 1;
        const int cx = cx0 + dx, cy = cy0 + dy, cz = cz0 + dz;
        int row = ZROW;
        if ((unsigned)(cx | cy | cz) < 64u){
            int pidx = pg[(cx >> 1) * 1024 + (cy >> 1) * 32 + (cz >> 1)];
            if (pidx >= 0)
                row = CHILD ? pidx * 8 + (((cx & 1) << 2) | ((cy & 1) << 1) | (cz & 1))
                            : pidx;
        }
        rows[t - TBEG] = row;
    }
#pragma unroll
    for (int t = TBEG; t < TEND; t++){
        int fr0 = __shfl(rows[t - TBEG],      r16, 64);
        int fr1 = __shfl(rows[t - TBEG], 16 + r16, 64);
        int fr2 = __shfl(rows[t - TBEG], 32 + r16, 64);
        int fr3 = __shfl(rows[t - TBEG], 48 + r16, 64);
        const ushort* a0 = feat + (size_t)fr0 * CIN + qd * 8;
        const ushort* a1 = feat + (size_t)fr1 * CIN + qd * 8;
        const ushort* a2 = feat + (size_t)fr2 * CIN + qd * 8;
        const ushort* a3 = feat + (size_t)fr3 * CIN + qd * 8;
        const ushort* wt = Wt + (size_t)t * (KB * 2048) + l * 8;
#pragma unroll
        for (int kb = 0; kb < KB; kb++){
            short8 b0 = *(const short8*)(wt + (kb*4+0)*512);
            short8 b1 = *(const short8*)(wt + (kb*4+1)*512);
            short8 b2 = *(const short8*)(wt + (kb*4+2)*512);
            short8 b3 = *(const short8*)(wt + (kb*4+3)*512);
            short8 av0 = *(const short8*)(a0 + kb*32);
            short8 av1 = *(const short8*)(a1 + kb*32);
            short8 av2 = *(const short8*)(a2 + kb*32);
            short8 av3 = *(const short8*)(a3 + kb*32);
            acc[0]  = __builtin_amdgcn_mfma_f32_16x16x32_bf16(av0, b0, acc[0],  0, 0, 0);
            acc[1]  = __builtin_amdgcn_mfma_f32_16x16x32_bf16(av0, b1, acc[1],  0, 0, 0);
            acc[2]  = __builtin_amdgcn_mfma_f32_16x16x32_bf16(av0, b2, acc[2],  0, 0, 0);
            acc[3]  = __builtin_amdgcn_mfma_f32_16x16x32_bf16(av0, b3, acc[3],  0, 0, 0);
            acc[4]  = __builtin_amdgcn_mfma_f32_16x16x32_bf16(av1, b0, acc[4],  0, 0, 0);
            acc[5]  = __builtin_amdgcn_mfma_f32_16x16x32_bf16(av1, b1, acc[5],  0, 0, 0);
            acc[6]  = __builtin_amdgcn_mfma_f32_16x16x32_bf16(av1, b2, acc[6],  0, 0, 0);
            acc[7]  = __builtin_amdgcn_mfma_f32_16x16x32_bf16(av1, b3, acc[7],  0, 0, 0);
            acc[8]  = __builtin_amdgcn_mfma_f32_16x16x32_bf16(av2, b0, acc[8],  0, 0, 0);
            acc[9]  = __builtin_amdgcn_mfma_f32_16x16x32_bf16(av2, b1, acc[9],  0, 0, 0);
            acc[10] = __builtin_amdgcn_mfma_f32_16x16x32_bf16(av2, b2, acc[10], 0, 0, 0);
            acc[11] = __builtin_amdgcn_mfma_f32_16x16x32_bf16(av2, b3, acc[11], 0, 0, 0);
            acc[12] = __builtin_amdgcn_mfma_f32_16x16x32_bf16(av3, b0, acc[12], 0, 0, 0);
            acc[13] = __builtin_amdgcn_mfma_f32_16x16x32_bf16(av3, b1, acc[13], 0, 0, 0);
            acc[14] = __builtin_amdgcn_mfma_f32_16x16x32_bf16(av3, b2, acc[14], 0, 0, 0);
            acc[15] = __builtin_amdgcn_mfma_f32_16x16x32_bf16(av3, b3, acc[15], 0, 0, 0);
        }
    }
}

template<int CIN, int CHILD>
__global__ void __launch_bounds__(128, 4) conv_direct(
    const ushort* __restrict__ feat, const int* __restrict__ pg,
    const int* __restrict__ coords, const ushort* __restrict__ Wt,
    const float* __restrict__ bias, const float* __restrict__ skip,
    ushort* __restrict__ hf1_bf, float* __restrict__ out, float* __restrict__ statsAcc)
{
    __shared__ float4v lacc[16][64];     // 16 KB partial-acc exchange
    const int tid = threadIdx.x;
    const int wid = tid >> 6, l = tid & 63;
    const int r16 = l & 15, qd = l >> 4;
    const int mb = blockIdx.x * 64;

    // this lane's child coords (child mb + l)
    int cx0, cy0, cz0;
    {
        int m = mb + l, p = m >> 3, o = m & 7;
        cx0 = 2 * coords[p*4+1] + ((o >> 2) & 1);
        cy0 = 2 * coords[p*4+2] + ((o >> 1) & 1);
        cz0 = 2 * coords[p*4+3] + (o & 1);
    }

    float4v acc[16];
#pragma unroll
    for (int c = 0; c < 16; c++) acc[c] = 0.f;

    if (wid == 0)
        conv_taps<CIN, CHILD, 0, 14>(feat, pg, Wt, cx0, cy0, cz0, l, r16, qd, acc);
    else
        conv_taps<CIN, CHILD, 14, 27>(feat, pg, Wt, cx0, cy0, cz0, l, r16, qd, acc);

    if (wid == 1){
#pragma unroll
        for (int c = 0; c < 16; c++) lacc[c][l] = acc[c];
    }
    __syncthreads();
    if (wid == 1) return;
#pragma unroll
    for (int c = 0; c < 16; c++) acc[c] += lacc[c][l];

    // epilogue (wave 0 only): C/D layout col = lane&15, row = (lane>>4)*4 + reg
    float bsv[4] = { bias[r16], bias[16 + r16], bias[32 + r16], bias[48 + r16] };
    if (!CHILD){
        float ps[4] = {0,0,0,0}, pq[4] = {0,0,0,0};
#pragma unroll
        for (int rb = 0; rb < 4; rb++)
#pragma unroll
            for (int nb = 0; nb < 4; nb++)
#pragma unroll
                for (int rg = 0; rg < 4; rg++){
                    int mm = mb + rb * 16 + qd * 4 + rg;
                    float v = acc[rb * 4 + nb][rg] + bsv[nb];
                    hf1_bf[(size_t)mm * 64 + nb * 16 + r16] = f2bf(v);
                    ps[nb] += v; pq[nb] += v * v;
                }
#pragma unroll
        for (int nb = 0; nb < 4; nb++){
            float s1 = ps[nb], s2 = pq[nb];
            s1 += __shfl_xor(s1, 16, 64); s2 += __shfl_xor(s2, 16, 64);
            s1 += __shfl_xor(s1, 32, 64); s2 += __shfl_xor(s2, 32, 64);
            if (qd == 0){
                atomicAdd(&statsAcc[64 + nb * 16 + r16], s1);
                atomicAdd(&statsAcc[128 + nb * 16 + r16], s2);
            }
        }
    } else {
#pragma unroll
        for (int rb = 0; rb < 4; rb++)
#pragma unroll
            for (int rg = 0; rg < 4; rg++){
                int mm = mb + rb * 16 + qd * 4 + rg;
                const float* sk = skip + (size_t)(mm >> 3) * 64;
#pragma unroll
                for (int nb = 0; nb < 4; nb++){
                    int co = nb * 16 + r16;
                    out[(size_t)mm * 64 + co] = acc[rb * 4 + nb][rg] + bsv[nb] + sk[co];
                }
            }
    }
}

// ================= K4: h2 = silu(gn2(hf1_bf16)) -> bf16 =================
__global__ void __launch_bounds__(256) h2_kernel(
    const ushort* __restrict__ hf1, const float* __restrict__ stats,
    const float* __restrict__ gg, const float* __restrict__ gb, ushort* __restrict__ h2)
{
    int i = (blockIdx.x * 256 + threadIdx.x) * 4;
    if (i >= M_PTS * C_OUT) return;
    int c0 = i & (C_OUT - 1);                    // multiple of 4
    const float inv = 1.0f / (M_PTS * 2.0f);
    float muA = (stats[64 + c0] + stats[64 + c0 + 1]) * inv;
    float vA  = (stats[128 + c0] + stats[128 + c0 + 1]) * inv - muA * muA;
    float rsA = rsqrtf(vA + EPS);
    float muB = (stats[64 + c0 + 2] + stats[64 + c0 + 3]) * inv;
    float vB  = (stats[128 + c0 + 2] + stats[128 + c0 + 3]) * inv - muB * muB;
    float rsB = rsqrtf(vB + EPS);
    ushort4 u = *(const ushort4*)(hf1 + i);
    ushort4 o;
    o.x = f2bf(silu((bf2f(u.x) - muA) * rsA * gg[c0+0] + gb[c0+0]));
    o.y = f2bf(silu((bf2f(u.y) - muA) * rsA * gg[c0+1] + gb[c0+1]));
    o.z = f2bf(silu((bf2f(u.z) - muB) * rsB * gg[c0+2] + gb[c0+2]));
    o.w = f2bf(silu((bf2f(u.w) - muB) * rsB * gg[c0+3] + gb[c0+3]));
    *(ushort4*)(h2 + i) = o;
}

extern "C" void kernel_launch(void* const* d_in, const int* in_sizes, int n_in,
                              void* d_out, int out_size, void* d_ws, size_t ws_size,
                              hipStream_t stream){
    const float* x   = (const float*)d_in[0];
    const int*   cds = (const int*)  d_in[1];
    const float* g1  = (const float*)d_in[2];
    const float* b1  = (const float*)d_in[3];
    const float* W1  = (const float*)d_in[4];
    const float* bb1 = (const float*)d_in[5];
    const float* g2  = (const float*)d_in[6];
    const float* b2  = (const float*)d_in[7];
    const float* W2  = (const float*)d_in[8];
    const float* bb2 = (const float*)d_in[9];
    const float* Wsk = (const float*)d_in[10];
    const float* bsk = (const float*)d_in[11];
    float* out = (float*)d_out;
    char* ws = (char*)d_ws;

    // workspace layout (16B-aligned)
    float*  stats = (float*) (ws);                 // 192 f32 (zeroed via memsetAsync)
    int*    pg    = (int*)   (ws + 1024);          // 131072 B -> 132096
    ushort* h     = (ushort*)(ws + 132096);        // (N+1)*128 bf16 = 5,120,256 -> 5,252,352
    ushort* h2    = (ushort*)(ws + 5252352);       // (M+1)*64 bf16 = 20,480,128 -> 25,732,480
    float*  s     = (float*) (ws + 25732480);      // N*64 f32 = 5,120,000 -> 30,852,480
    ushort* Wt1   = (ushort*)(ws + 30852480);      // 442,368 -> 31,294,848
    ushort* Wt2   = (ushort*)(ws + 31294848);      // 221,184 -> 31,516,032
    // hf1 (bf16, M*64) lives in d_out between conv1 and h2_kernel; conv2 overwrites d_out as f32.

    hipMemsetAsync(stats, 0, 192 * sizeof(float), stream);
    prep_kernel<<<1936, 256, 0, stream>>>(W1, W2, Wt1, Wt2, pg, h, h2, x, stats);
    mid_kernel<<<7579, 256, 0, stream>>>(cds, pg, x, stats, g1, b1, h, Wsk, bsk, s);
    conv_direct<C_IN, 0><<<2500, 128, 0, stream>>>(h, pg, cds, Wt1, bb1, nullptr,
                                                   (ushort*)d_out, nullptr, stats);
    h2_kernel<<<12500, 256, 0, stream>>>((const ushort*)d_out, stats, g2, b2, h2);
    conv_direct<C_OUT, 1><<<2500, 128, 0, stream>>>(h2, pg, cds, Wt2, bb2, s,
                                                    nullptr, out, nullptr);
}

// Round 5
// 352.682 us; speedup vs baseline: 1.2791x; 1.2791x over previous
//
#include <hip/hip_runtime.h>
#include <hip/hip_bf16.h>
#include <math.h>

#define N_PTS 20000
#define C_IN 128
#define C_OUT 64
#define M_PTS (N_PTS*8)
#define EPS 1e-5f

typedef __attribute__((ext_vector_type(8))) short short8;
typedef __attribute__((ext_vector_type(4))) float float4v;

__device__ __forceinline__ ushort f2bf(float f){
    unsigned int i = __float_as_uint(f);
    unsigned int r = i + 0x7fffu + ((i >> 16) & 1u);
    return (ushort)(r >> 16);
}
__device__ __forceinline__ float bf2f(ushort u){ return __uint_as_float(((unsigned int)u) << 16); }
__device__ __forceinline__ float silu(float z){ return z / (1.f + expf(-z)); }

// stats layout (fp32, ws): [0..31] gn1 group sum, [32..63] gn1 group sumsq,
//                          [64..127] gn2 ch sum, [128..191] gn2 ch sumsq

// ================= K1: W1eff + wprep2 + pg_init(+zero rows) + gn1_partial =================
// blocks: [0,2048) W1eff, [2048,2480) Wt2, [2480,2608) pg_init, [2608,3120) gn1
// W1eff[o][j] = sum over taps d with per-axis (o_x+d_x)>>1 == o_x+j_x-1 of W1[d].
__global__ void __launch_bounds__(256) prep_kernel(
    const float* __restrict__ W1, const float* __restrict__ W2,
    ushort* __restrict__ Wt1, ushort* __restrict__ Wt2,
    int* __restrict__ pg, ushort* __restrict__ h, ushort* __restrict__ h2,
    const float* __restrict__ x, float* __restrict__ stats)
{
    const int b = blockIdx.x, tid = threadIdx.x;
    if (b < 2048){
        // Wt1eff fragment order: idx = (((t*4+kb)*4+nb)*64+l)*8+j, t = o*8+jj in [0,64)
        int idx = b * 256 + tid;
        int j = idx & 7, l = (idx >> 3) & 63, nb = (idx >> 9) & 3, kb = (idx >> 11) & 3, t = idx >> 13;
        int ci = kb * 32 + (l >> 4) * 8 + j, co = nb * 16 + (l & 15);
        int o = t >> 3, jj = t & 7;
        int ox = (o >> 2) & 1, oy = (o >> 1) & 1, oz = o & 1;
        int jx = (jj >> 2) & 1, jy = (jj >> 1) & 1, jz = jj & 1;
        float s = 0.f;
#pragma unroll
        for (int dx = -1; dx <= 1; dx++){
            if (((ox + dx) >> 1) != ox + jx - 1) continue;
#pragma unroll
            for (int dy = -1; dy <= 1; dy++){
                if (((oy + dy) >> 1) != oy + jy - 1) continue;
#pragma unroll
                for (int dz = -1; dz <= 1; dz++){
                    if (((oz + dz) >> 1) != oz + jz - 1) continue;
                    s += W1[((dx+1)*9 + (dy+1)*3 + (dz+1)) * (C_IN*64) + ci * 64 + co];
                }
            }
        }
        Wt1[idx] = f2bf(s);
    } else if (b < 2480){
        // Wt2 fragment order: idx = (((t*2+kb)*4+nb)*64+l)*8+j, KB=2, t in [0,27)
        int idx = (b - 2048) * 256 + tid;
        int j = idx & 7, l = (idx >> 3) & 63, nb = (idx >> 9) & 3, kb = (idx >> 11) & 1, t = idx >> 12;
        int ci = kb * 32 + (l >> 4) * 8 + j, co = nb * 16 + (l & 15);
        Wt2[idx] = f2bf(W2[(t * C_OUT + ci) * 64 + co]);
    } else if (b < 2608){
        int i = (b - 2480) * 256 + tid;
        pg[i] = -1;
        if (b == 2480){
            if (tid < C_IN) h[(size_t)N_PTS * C_IN + tid] = 0;    // zero parent row (conv1)
            if (tid < 256){                                        // 8 zero child rows (conv2)
                h2[(size_t)M_PTS * C_OUT + tid] = 0;
                h2[(size_t)M_PTS * C_OUT + 256 + tid] = 0;
            }
        }
    } else {
        // gn1 partial: 512 blocks, grid-stride rows, LDS + global atomics
        __shared__ float ls[64];
        if (tid < 64) ls[tid] = 0.f;
        __syncthreads();
        const int g = tid & 31;
        const int r0 = (b - 2608) * 8 + (tid >> 5);
        float sum = 0.f, sq = 0.f;
        for (int r = r0; r < N_PTS; r += 4096){
            float4 v = *(const float4*)(x + (size_t)r * C_IN + g * 4);
            sum += v.x + v.y + v.z + v.w;
            sq  += v.x*v.x + v.y*v.y + v.z*v.z + v.w*v.w;
        }
        atomicAdd(&ls[g], sum);
        atomicAdd(&ls[32 + g], sq);
        __syncthreads();
        if (tid < 64) atomicAdd(&stats[tid], ls[tid]);
    }
}

// ================= K2: pg_scatter + h_compute + skip =================
// blocks: [0,79) scatter, [79,2579) h (vec4), [2579,7579) skip
__global__ void __launch_bounds__(256) mid_kernel(
    const int* __restrict__ cds, int* __restrict__ pg,
    const float* __restrict__ x, const float* __restrict__ stats,
    const float* __restrict__ g1, const float* __restrict__ b1, ushort* __restrict__ h,
    const float* __restrict__ Wsk, const float* __restrict__ bsk, float* __restrict__ s)
{
    __shared__ float w[C_IN * C_OUT];
    const int b = blockIdx.x, tid = threadIdx.x;
    if (b < 79){
        int i = b * 256 + tid;
        if (i < N_PTS){
            const int* cd = cds + i * 4;
            pg[(cd[1] * 32 + cd[2]) * 32 + cd[3]] = i;
        }
    } else if (b < 2579){
        int i = ((b - 79) * 256 + tid) * 4;
        int c0 = i & (C_IN - 1);                  // multiple of 4 -> one group
        int g = c0 >> 2;
        float mu = stats[g] * (1.0f / (N_PTS * 4.0f));
        float var = stats[32 + g] * (1.0f / (N_PTS * 4.0f)) - mu * mu;
        float rs = rsqrtf(var + EPS);
        float4 v = *(const float4*)(x + i);
        ushort4 o;
        o.x = f2bf(silu((v.x - mu) * rs * g1[c0+0] + b1[c0+0]));
        o.y = f2bf(silu((v.y - mu) * rs * g1[c0+1] + b1[c0+1]));
        o.z = f2bf(silu((v.z - mu) * rs * g1[c0+2] + b1[c0+2]));
        o.w = f2bf(silu((v.w - mu) * rs * g1[c0+3] + b1[c0+3]));
        *(ushort4*)(h + i) = o;
    } else {
        for (int j = tid; j < C_IN * C_OUT; j += 256) w[j] = Wsk[j];
        __syncthreads();
        int co = tid & 63, pr = tid >> 6;
        int p = (b - 2579) * 4 + pr;
        const float* xr = x + (size_t)p * C_IN;
        float a = bsk[co];
        for (int cb = 0; cb < C_IN; cb += 4){
            float4 v = *(const float4*)(xr + cb);
            a += v.x * w[(cb+0)*64+co] + v.y * w[(cb+1)*64+co]
               + v.z * w[(cb+2)*64+co] + v.w * w[(cb+3)*64+co];
        }
        s[(size_t)p * C_OUT + co] = a;
    }
}

// ================= conv1: corner-collapsed implicit GEMM =================
// grid (313, 8): blockIdx.x = 64-parent tile, blockIdx.y = octant o.
// M-tile = 64 parents (children (p,o)), N = 64, 8 corner taps of K=128 with W1eff.
// A rows = parent feature rows (h). 8 pg lookups per lane, hoisted; shfl exchange.
// Fused: bias, hf1 bf16 write, GN2 partial sums (padding rows excluded).
__global__ void __launch_bounds__(64, 3) conv1_corner(
    const ushort* __restrict__ feat, const int* __restrict__ pg,
    const int* __restrict__ coords, const ushort* __restrict__ Wt,
    const float* __restrict__ bias, ushort* __restrict__ hf1_bf,
    float* __restrict__ statsAcc)
{
    const int l = threadIdx.x;
    const int r16 = l & 15, qd = l >> 4;
    const int bx = blockIdx.x, o = blockIdx.y;

    int p = bx * 64 + l;
    int pc = p < N_PTS ? p : N_PTS - 1;
    int px = coords[pc*4+1], py = coords[pc*4+2], pz = coords[pc*4+3];
    // corner base: e = o_bit - 1 + j_bit per axis
    int ex0 = px + ((o >> 2) & 1) - 1;
    int ey0 = py + ((o >> 1) & 1) - 1;
    int ez0 = pz + (o & 1) - 1;

    int rows8[8];
#pragma unroll
    for (int j = 0; j < 8; j++){
        int cx = ex0 + ((j >> 2) & 1), cy = ey0 + ((j >> 1) & 1), cz = ez0 + (j & 1);
        int row = N_PTS;
        if ((unsigned)cx < 32u && (unsigned)cy < 32u && (unsigned)cz < 32u){
            int pi = pg[cx * 1024 + cy * 32 + cz];
            if (pi >= 0) row = pi;
        }
        rows8[j] = row;
    }

    float4v acc[16];
#pragma unroll
    for (int c = 0; c < 16; c++) acc[c] = 0.f;

#pragma unroll
    for (int j = 0; j < 8; j++){
        int fr0 = __shfl(rows8[j],      r16, 64);
        int fr1 = __shfl(rows8[j], 16 + r16, 64);
        int fr2 = __shfl(rows8[j], 32 + r16, 64);
        int fr3 = __shfl(rows8[j], 48 + r16, 64);
        const ushort* a0 = feat + (size_t)fr0 * C_IN + qd * 8;
        const ushort* a1 = feat + (size_t)fr1 * C_IN + qd * 8;
        const ushort* a2 = feat + (size_t)fr2 * C_IN + qd * 8;
        const ushort* a3 = feat + (size_t)fr3 * C_IN + qd * 8;
        const ushort* wt = Wt + (size_t)(o * 8 + j) * 8192 + l * 8;
#pragma unroll
        for (int kb = 0; kb < 4; kb++){
            short8 b0 = *(const short8*)(wt + (kb*4+0)*512);
            short8 b1 = *(const short8*)(wt + (kb*4+1)*512);
            short8 b2 = *(const short8*)(wt + (kb*4+2)*512);
            short8 b3 = *(const short8*)(wt + (kb*4+3)*512);
            short8 av0 = *(const short8*)(a0 + kb*32);
            short8 av1 = *(const short8*)(a1 + kb*32);
            short8 av2 = *(const short8*)(a2 + kb*32);
            short8 av3 = *(const short8*)(a3 + kb*32);
            acc[0]  = __builtin_amdgcn_mfma_f32_16x16x32_bf16(av0, b0, acc[0],  0, 0, 0);
            acc[1]  = __builtin_amdgcn_mfma_f32_16x16x32_bf16(av0, b1, acc[1],  0, 0, 0);
            acc[2]  = __builtin_amdgcn_mfma_f32_16x16x32_bf16(av0, b2, acc[2],  0, 0, 0);
            acc[3]  = __builtin_amdgcn_mfma_f32_16x16x32_bf16(av0, b3, acc[3],  0, 0, 0);
            acc[4]  = __builtin_amdgcn_mfma_f32_16x16x32_bf16(av1, b0, acc[4],  0, 0, 0);
            acc[5]  = __builtin_amdgcn_mfma_f32_16x16x32_bf16(av1, b1, acc[5],  0, 0, 0);
            acc[6]  = __builtin_amdgcn_mfma_f32_16x16x32_bf16(av1, b2, acc[6],  0, 0, 0);
            acc[7]  = __builtin_amdgcn_mfma_f32_16x16x32_bf16(av1, b3, acc[7],  0, 0, 0);
            acc[8]  = __builtin_amdgcn_mfma_f32_16x16x32_bf16(av2, b0, acc[8],  0, 0, 0);
            acc[9]  = __builtin_amdgcn_mfma_f32_16x16x32_bf16(av2, b1, acc[9],  0, 0, 0);
            acc[10] = __builtin_amdgcn_mfma_f32_16x16x32_bf16(av2, b2, acc[10], 0, 0, 0);
            acc[11] = __builtin_amdgcn_mfma_f32_16x16x32_bf16(av2, b3, acc[11], 0, 0, 0);
            acc[12] = __builtin_amdgcn_mfma_f32_16x16x32_bf16(av3, b0, acc[12], 0, 0, 0);
            acc[13] = __builtin_amdgcn_mfma_f32_16x16x32_bf16(av3, b1, acc[13], 0, 0, 0);
            acc[14] = __builtin_amdgcn_mfma_f32_16x16x32_bf16(av3, b2, acc[14], 0, 0, 0);
            acc[15] = __builtin_amdgcn_mfma_f32_16x16x32_bf16(av3, b3, acc[15], 0, 0, 0);
        }
    }

    // epilogue: C/D layout col = lane&15, row = (lane>>4)*4 + reg; row-in-tile = parent
    float bsv[4] = { bias[r16], bias[16 + r16], bias[32 + r16], bias[48 + r16] };
    float ps[4] = {0,0,0,0}, pq[4] = {0,0,0,0};
#pragma unroll
    for (int rb = 0; rb < 4; rb++)
#pragma unroll
        for (int nb = 0; nb < 4; nb++)
#pragma unroll
            for (int rg = 0; rg < 4; rg++){
                int pr = bx * 64 + rb * 16 + qd * 4 + rg;
                float v = acc[rb * 4 + nb][rg] + bsv[nb];
                if (pr < N_PTS){
                    hf1_bf[(size_t)(pr * 8 + o) * 64 + nb * 16 + r16] = f2bf(v);
                    ps[nb] += v; pq[nb] += v * v;
                }
            }
#pragma unroll
    for (int nb = 0; nb < 4; nb++){
        float s1 = ps[nb], s2 = pq[nb];
        s1 += __shfl_xor(s1, 16, 64); s2 += __shfl_xor(s2, 16, 64);
        s1 += __shfl_xor(s1, 32, 64); s2 += __shfl_xor(s2, 32, 64);
        if (qd == 0){
            atomicAdd(&statsAcc[64 + nb * 16 + r16], s1);
            atomicAdd(&statsAcc[128 + nb * 16 + r16], s2);
        }
    }
}

// ================= conv2: corner-based implicit GEMM =================
// grid (313, 8). M-tile = 64 children (64 parents, fixed octant o), N=64, 27 taps K=64.
// Only 8 pg lookups; tap t's A row = pidx8[j(o,t)]*8 + o'(o,t) via constant-index
// select tree (j bits are block-uniform). Adds skip, writes fp32 out.
__global__ void __launch_bounds__(64, 3) conv2_corner(
    const ushort* __restrict__ feat, const int* __restrict__ pg,
    const int* __restrict__ coords, const ushort* __restrict__ Wt,
    const float* __restrict__ bias, const float* __restrict__ skip,
    float* __restrict__ out)
{
    const int l = threadIdx.x;
    const int r16 = l & 15, qd = l >> 4;
    const int bx = blockIdx.x, o = blockIdx.y;
    const int ox = (o >> 2) & 1, oy = (o >> 1) & 1, oz = o & 1;

    int p = bx * 64 + l;
    int pc = p < N_PTS ? p : N_PTS - 1;
    int px = coords[pc*4+1], py = coords[pc*4+2], pz = coords[pc*4+3];
    int ex0 = px + ox - 1, ey0 = py + oy - 1, ez0 = pz + oz - 1;

    int pb[8];   // child-row base per corner: pidx*8 or zero-block M_PTS
#pragma unroll
    for (int j = 0; j < 8; j++){
        int cx = ex0 + ((j >> 2) & 1), cy = ey0 + ((j >> 1) & 1), cz = ez0 + (j & 1);
        int base = M_PTS;
        if ((unsigned)cx < 32u && (unsigned)cy < 32u && (unsigned)cz < 32u){
            int pi = pg[cx * 1024 + cy * 32 + cz];
            if (pi >= 0) base = pi * 8;
        }
        pb[j] = base;
    }

    float4v acc[16];
#pragma unroll
    for (int c = 0; c < 16; c++) acc[c] = 0.f;

#pragma unroll
    for (int t = 0; t < 27; t++){
        const int dx = t / 9 - 1, dy = (t / 3) % 3 - 1, dz = t % 3 - 1;
        int sx = ox + dx, sy = oy + dy, sz = oz + dz;
        int jx = (sx >> 1) - ox + 1, jy = (sy >> 1) - oy + 1, jz = (sz >> 1) - oz + 1;
        int opi = (sx & 1) * 4 + (sy & 1) * 2 + (sz & 1);
        // constant-index select tree (jx/jy/jz block-uniform 0/1)
        int m00 = jz ? pb[1] : pb[0];
        int m01 = jz ? pb[3] : pb[2];
        int m10 = jz ? pb[5] : pb[4];
        int m11 = jz ? pb[7] : pb[6];
        int n0 = jy ? m01 : m00;
        int n1 = jy ? m11 : m10;
        int row = (jx ? n1 : n0) + opi;
        int fr0 = __shfl(row,      r16, 64);
        int fr1 = __shfl(row, 16 + r16, 64);
        int fr2 = __shfl(row, 32 + r16, 64);
        int fr3 = __shfl(row, 48 + r16, 64);
        const ushort* a0 = feat + (size_t)fr0 * C_OUT + qd * 8;
        const ushort* a1 = feat + (size_t)fr1 * C_OUT + qd * 8;
        const ushort* a2 = feat + (size_t)fr2 * C_OUT + qd * 8;
        const ushort* a3 = feat + (size_t)fr3 * C_OUT + qd * 8;
        const ushort* wt = Wt + (size_t)t * 4096 + l * 8;
#pragma unroll
        for (int kb = 0; kb < 2; kb++){
            short8 b0 = *(const short8*)(wt + (kb*4+0)*512);
            short8 b1 = *(const short8*)(wt + (kb*4+1)*512);
            short8 b2 = *(const short8*)(wt + (kb*4+2)*512);
            short8 b3 = *(const short8*)(wt + (kb*4+3)*512);
            short8 av0 = *(const short8*)(a0 + kb*32);
            short8 av1 = *(const short8*)(a1 + kb*32);
            short8 av2 = *(const short8*)(a2 + kb*32);
            short8 av3 = *(const short8*)(a3 + kb*32);
            acc[0]  = __builtin_amdgcn_mfma_f32_16x16x32_bf16(av0, b0, acc[0],  0, 0, 0);
            acc[1]  = __builtin_amdgcn_mfma_f32_16x16x32_bf16(av0, b1, acc[1],  0, 0, 0);
            acc[2]  = __builtin_amdgcn_mfma_f32_16x16x32_bf16(av0, b2, acc[2],  0, 0, 0);
            acc[3]  = __builtin_amdgcn_mfma_f32_16x16x32_bf16(av0, b3, acc[3],  0, 0, 0);
            acc[4]  = __builtin_amdgcn_mfma_f32_16x16x32_bf16(av1, b0, acc[4],  0, 0, 0);
            acc[5]  = __builtin_amdgcn_mfma_f32_16x16x32_bf16(av1, b1, acc[5],  0, 0, 0);
            acc[6]  = __builtin_amdgcn_mfma_f32_16x16x32_bf16(av1, b2, acc[6],  0, 0, 0);
            acc[7]  = __builtin_amdgcn_mfma_f32_16x16x32_bf16(av1, b3, acc[7],  0, 0, 0);
            acc[8]  = __builtin_amdgcn_mfma_f32_16x16x32_bf16(av2, b0, acc[8],  0, 0, 0);
            acc[9]  = __builtin_amdgcn_mfma_f32_16x16x32_bf16(av2, b1, acc[9],  0, 0, 0);
            acc[10] = __builtin_amdgcn_mfma_f32_16x16x32_bf16(av2, b2, acc[10], 0, 0, 0);
            acc[11] = __builtin_amdgcn_mfma_f32_16x16x32_bf16(av2, b3, acc[11], 0, 0, 0);
            acc[12] = __builtin_amdgcn_mfma_f32_16x16x32_bf16(av3, b0, acc[12], 0, 0, 0);
            acc[13] = __builtin_amdgcn_mfma_f32_16x16x32_bf16(av3, b1, acc[13], 0, 0, 0);
            acc[14] = __builtin_amdgcn_mfma_f32_16x16x32_bf16(av3, b2, acc[14], 0, 0, 0);
            acc[15] = __builtin_amdgcn_mfma_f32_16x16x32_bf16(av3, b3, acc[15], 0, 0, 0);
        }
    }

    float bsv[4] = { bias[r16], bias[16 + r16], bias[32 + r16], bias[48 + r16] };
#pragma unroll
    for (int rb = 0; rb < 4; rb++)
#pragma unroll
        for (int rg = 0; rg < 4; rg++){
            int pr = bx * 64 + rb * 16 + qd * 4 + rg;
            if (pr < N_PTS){
                const float* sk = skip + (size_t)pr * 64;
#pragma unroll
                for (int nb = 0; nb < 4; nb++){
                    int co = nb * 16 + r16;
                    out[(size_t)(pr * 8 + o) * 64 + co] = acc[rb * 4 + nb][rg] + bsv[nb] + sk[co];
                }
            }
        }
}

// ================= K4: h2 = silu(gn2(hf1_bf16)) -> bf16 =================
__global__ void __launch_bounds__(256) h2_kernel(
    const ushort* __restrict__ hf1, const float* __restrict__ stats,
    const float* __restrict__ gg, const float* __restrict__ gb, ushort* __restrict__ h2)
{
    int i = (blockIdx.x * 256 + threadIdx.x) * 4;
    if (i >= M_PTS * C_OUT) return;
    int c0 = i & (C_OUT - 1);                    // multiple of 4
    const float inv = 1.0f / (M_PTS * 2.0f);
    float muA = (stats[64 + c0] + stats[64 + c0 + 1]) * inv;
    float vA  = (stats[128 + c0] + stats[128 + c0 + 1]) * inv - muA * muA;
    float rsA = rsqrtf(vA + EPS);
    float muB = (stats[64 + c0 + 2] + stats[64 + c0 + 3]) * inv;
    float vB  = (stats[128 + c0 + 2] + stats[128 + c0 + 3]) * inv - muB * muB;
    float rsB = rsqrtf(vB + EPS);
    ushort4 u = *(const ushort4*)(hf1 + i);
    ushort4 o;
    o.x = f2bf(silu((bf2f(u.x) - muA) * rsA * gg[c0+0] + gb[c0+0]));
    o.y = f2bf(silu((bf2f(u.y) - muA) * rsA * gg[c0+1] + gb[c0+1]));
    o.z = f2bf(silu((bf2f(u.z) - muB) * rsB * gg[c0+2] + gb[c0+2]));
    o.w = f2bf(silu((bf2f(u.w) - muB) * rsB * gg[c0+3] + gb[c0+3]));
    *(ushort4*)(h2 + i) = o;
}

extern "C" void kernel_launch(void* const* d_in, const int* in_sizes, int n_in,
                              void* d_out, int out_size, void* d_ws, size_t ws_size,
                              hipStream_t stream){
    const float* x   = (const float*)d_in[0];
    const int*   cds = (const int*)  d_in[1];
    const float* g1  = (const float*)d_in[2];
    const float* b1  = (const float*)d_in[3];
    const float* W1  = (const float*)d_in[4];
    const float* bb1 = (const float*)d_in[5];
    const float* g2  = (const float*)d_in[6];
    const float* b2  = (const float*)d_in[7];
    const float* W2  = (const float*)d_in[8];
    const float* bb2 = (const float*)d_in[9];
    const float* Wsk = (const float*)d_in[10];
    const float* bsk = (const float*)d_in[11];
    float* out = (float*)d_out;
    char* ws = (char*)d_ws;

    // workspace layout (16B-aligned)
    float*  stats = (float*) (ws);                 // 192 f32 (zeroed via memsetAsync)
    int*    pg    = (int*)   (ws + 1024);          // 131072 B -> 132096
    ushort* h     = (ushort*)(ws + 132096);        // (N+1)*128 bf16 = 5,120,256 -> 5,252,352
    ushort* h2    = (ushort*)(ws + 5252352);       // (M+8)*64 bf16 = 20,481,024 -> 25,733,376
    float*  s     = (float*) (ws + 25733376);      // N*64 f32 = 5,120,000 -> 30,853,376
    ushort* Wt1   = (ushort*)(ws + 30853376);      // W1eff 64*8192*2 = 1,048,576 -> 31,901,952
    ushort* Wt2   = (ushort*)(ws + 31901952);      // 221,184 -> 32,123,136
    // hf1 (bf16, M*64) lives in d_out between conv1 and h2_kernel; conv2 overwrites d_out as f32.

    hipMemsetAsync(stats, 0, 192 * sizeof(float), stream);
    prep_kernel<<<3120, 256, 0, stream>>>(W1, W2, Wt1, Wt2, pg, h, h2, x, stats);
    mid_kernel<<<7579, 256, 0, stream>>>(cds, pg, x, stats, g1, b1, h, Wsk, bsk, s);
    conv1_corner<<<dim3(313, 8), 64, 0, stream>>>(h, pg, cds, Wt1, bb1,
                                                  (ushort*)d_out, stats);
    h2_kernel<<<12500, 256, 0, stream>>>((const ushort*)d_out, stats, g2, b2, h2);
    conv2_corner<<<dim3(313, 8), 64, 0, stream>>>(h2, pg, cds, Wt2, bb2, s, out);
}